// Round 5
// baseline (42.653 us; speedup 1.0000x reference)
//
#include <hip/hip_runtime.h>

namespace {
constexpr int B = 4, Te = 512, Td = 128, Den = 256, Dde = 512, U = 128;
constexpr float REMOVE = 1000000.0f;
constexpr float L2E2 = 2.885390081777927f;  // 2*log2(e)

__device__ __forceinline__ unsigned short f2bf(float f) {
  unsigned u = __float_as_uint(f);
  u += 0x7FFFu + ((u >> 16) & 1u);      // RNE
  return (unsigned short)(u >> 16);
}
__device__ __forceinline__ float bf2f(unsigned short h) {
  return __uint_as_float(((unsigned)h) << 16);
}
// acc += tanh(ep+dv)*nv ; tanh = 1 - 2/(exp(2x)+1), inf-safe both tails
__device__ __forceinline__ void tanh_fma(float ep, float dv, float nv, float& acc) {
  float e = __builtin_amdgcn_exp2f((ep + dv) * L2E2);
  float r = __builtin_amdgcn_rcpf(e + 1.0f);
  acc = fmaf(fmaf(-2.0f, r, 1.0f), nv, acc);
}
__device__ __forceinline__ void fma4(const float4& w, float x, float* a) {
  a[0] = fmaf(x, w.x, a[0]); a[1] = fmaf(x, w.y, a[1]);
  a[2] = fmaf(x, w.z, a[2]); a[3] = fmaf(x, w.w, a[3]);
}

// ---------------- K1: projections (384 blocks x 256 thr) ----------------
// blocks 0..255:   8 en rows -> en_pT (bf16 [b][u][te]) + masked bf16 en copy
// blocks 256..383: q=blk-256: rt=q>>1 (8 de rows), kh=q&1 (K-half)
//                  -> de_pA/de_pB + de pass-through to out (channel half kh)
__global__ __launch_bounds__(256) void proj_kernel(
    const float* __restrict__ en_seq, const float* __restrict__ de_seq,
    const int* __restrict__ mask, const float* __restrict__ w_en,
    const float* __restrict__ w_de, unsigned short* __restrict__ en_pT,
    unsigned short* __restrict__ en_bf, float* __restrict__ de_pA,
    float* __restrict__ de_pB, float* __restrict__ out) {
  __shared__ float xs[2048];            // 8 KiB: [8][256] staging / [8][128] acc
  const int blk = blockIdx.x, tid = threadIdx.x;

  if (blk < 256) {
    const int r0 = blk * 8;             // global encoder rows (b*Te+te)
    for (int i = tid; i < 512; i += 256) {
      int row = i >> 6, c4 = i & 63;
      float m = (float)mask[r0 + row];
      float4 v = *(const float4*)(en_seq + (size_t)(r0 + row) * Den + c4 * 4);
      v.x *= m; v.y *= m; v.z *= m; v.w *= m;
      *(float4*)(xs + row * 256 + c4 * 4) = v;
      ushort4 h; h.x = f2bf(v.x); h.y = f2bf(v.y); h.z = f2bf(v.z); h.w = f2bf(v.w);
      *(ushort4*)(en_bf + (size_t)(r0 + row) * Den + c4 * 4) = h;
    }
    __syncthreads();
    const int rg = tid >> 5, ug = tid & 31, u0 = ug * 4;
    float acc[4] = {0, 0, 0, 0};
#pragma unroll 4
    for (int k = 0; k < 256; k += 4) {
      const float* wp = w_en + (size_t)k * U + u0;
      float4 w0 = *(const float4*)(wp);
      float4 w1 = *(const float4*)(wp + U);
      float4 w2 = *(const float4*)(wp + 2 * U);
      float4 w3 = *(const float4*)(wp + 3 * U);
      float4 xv = *(const float4*)(xs + rg * 256 + k);
      fma4(w0, xv.x, acc); fma4(w1, xv.y, acc);
      fma4(w2, xv.z, acc); fma4(w3, xv.w, acc);
    }
    __syncthreads();                    // staging reads done; reuse xs [8][128]
    *(float4*)(xs + rg * 128 + u0) = make_float4(acc[0], acc[1], acc[2], acc[3]);
    __syncthreads();
    if (tid < 128) {                    // transposed bf16 write, coalesced-ish
      int u = tid;
      int b = r0 >> 9, te0 = r0 & 511;
      ushort4 h0, h1;
      h0.x = f2bf(xs[0 * 128 + u]); h0.y = f2bf(xs[1 * 128 + u]);
      h0.z = f2bf(xs[2 * 128 + u]); h0.w = f2bf(xs[3 * 128 + u]);
      h1.x = f2bf(xs[4 * 128 + u]); h1.y = f2bf(xs[5 * 128 + u]);
      h1.z = f2bf(xs[6 * 128 + u]); h1.w = f2bf(xs[7 * 128 + u]);
      unsigned short* dst = en_pT + ((size_t)b * U + u) * Te + te0;
      *(ushort4*)(dst) = h0;
      *(ushort4*)(dst + 4) = h1;
    }
  } else {
    const int q = blk - 256, rt = q >> 1, kh = q & 1;
    const int r0 = rt * 8, k0 = kh * 256;
    for (int i = tid; i < 512; i += 256) {  // stage K-half + pass-through
      int row = i >> 6, c4 = i & 63;
      float4 v = *(const float4*)(de_seq + (size_t)(r0 + row) * Dde + k0 + c4 * 4);
      *(float4*)(xs + row * 256 + c4 * 4) = v;
      *(float4*)(out + (size_t)(r0 + row) * 768 + k0 + c4 * 4) = v;
    }
    __syncthreads();
    const int rg = tid >> 5, ug = tid & 31, u0 = ug * 4;
    float acc[4] = {0, 0, 0, 0};
#pragma unroll 4
    for (int k = 0; k < 256; k += 4) {
      const float* wp = w_de + (size_t)(k0 + k) * U + u0;
      float4 w0 = *(const float4*)(wp);
      float4 w1 = *(const float4*)(wp + U);
      float4 w2 = *(const float4*)(wp + 2 * U);
      float4 w3 = *(const float4*)(wp + 3 * U);
      float4 xv = *(const float4*)(xs + rg * 256 + k);
      fma4(w0, xv.x, acc); fma4(w1, xv.y, acc);
      fma4(w2, xv.z, acc); fma4(w3, xv.w, acc);
    }
    float* dst = kh ? de_pB : de_pA;
    *(float4*)(dst + (size_t)(r0 + rg) * U + u0) =
        make_float4(acc[0], acc[1], acc[2], acc[3]);
  }
}

// ---------------- K2: per-(b,td) attention (512 blocks x 256 thr) ------
__global__ __launch_bounds__(256) void attn_kernel(
    const unsigned short* __restrict__ en_pT, const unsigned short* __restrict__ en_bf,
    const float* __restrict__ de_pA, const float* __restrict__ de_pB,
    const float* __restrict__ nu, const int* __restrict__ mask,
    float* __restrict__ out) {
  __shared__ float dep[128], nus[128], mbs[512], als[512];
  __shared__ float scr[1024];           // score partials [2][512] / sum [4][256]
  __shared__ float wredA[4], wredB[4];
  const int blk = blockIdx.x, tid = threadIdx.x;
  const int b = blk >> 7, gtd = blk;    // gtd = b*Td + td == blk

  mbs[tid]       = ((float)mask[b * Te + tid] - 1.0f) * REMOVE;
  mbs[tid + 256] = ((float)mask[b * Te + tid + 256] - 1.0f) * REMOVE;
  if (tid < 32) {
    float4 a = *(const float4*)(de_pA + (size_t)gtd * U + tid * 4);
    float4 c = *(const float4*)(de_pB + (size_t)gtd * U + tid * 4);
    *(float4*)(dep + tid * 4) =
        make_float4(a.x + c.x, a.y + c.y, a.z + c.z, a.w + c.w);
  } else if (tid < 64) {
    int q2 = tid - 32;
    *(float4*)(nus + q2 * 4) = *(const float4*)(nu + q2 * 4);
  }
  __syncthreads();

  {                                     // ---- scores ----
    const int ts = tid & 127, uq = tid >> 7;
    const int te0 = ts * 4;
    const unsigned short* ep = en_pT + (size_t)b * U * Te;
    float s[4] = {0, 0, 0, 0};
#pragma unroll 8
    for (int u = uq * 64; u < uq * 64 + 64; ++u) {
      ushort4 h = *(const ushort4*)(ep + (size_t)u * Te + te0);
      float dv = dep[u], nv = nus[u];
      tanh_fma(bf2f(h.x), dv, nv, s[0]);
      tanh_fma(bf2f(h.y), dv, nv, s[1]);
      tanh_fma(bf2f(h.z), dv, nv, s[2]);
      tanh_fma(bf2f(h.w), dv, nv, s[3]);
    }
    *(float4*)(scr + uq * 512 + te0) = make_float4(s[0], s[1], s[2], s[3]);
  }
  __syncthreads();

  {                                     // ---- softmax over Te=512 ----
    const int wid = tid >> 6;
    float v0 = scr[tid] + scr[512 + tid] + mbs[tid];
    float v1 = scr[tid + 256] + scr[512 + tid + 256] + mbs[tid + 256];
    float mx = fmaxf(v0, v1);
#pragma unroll
    for (int o = 32; o >= 1; o >>= 1) mx = fmaxf(mx, __shfl_xor(mx, o));
    if ((tid & 63) == 0) wredA[wid] = mx;
    __syncthreads();
    float bm = fmaxf(fmaxf(wredA[0], wredA[1]), fmaxf(wredA[2], wredA[3]));
    float e0 = __expf(v0 - bm), e1 = __expf(v1 - bm);
    float ss = e0 + e1;
#pragma unroll
    for (int o = 32; o >= 1; o >>= 1) ss += __shfl_xor(ss, o);
    if ((tid & 63) == 0) wredB[wid] = ss;
    __syncthreads();
    float inv = 1.0f / (wredB[0] + wredB[1] + wredB[2] + wredB[3]);
    als[tid] = e0 * inv;
    als[tid + 256] = e1 * inv;
  }
  __syncthreads();

  {                                     // ---- weighted sum ----
    const int cq = tid & 63, teq = tid >> 6;
    const int c0 = cq * 4;
    const unsigned short* eb = en_bf + (size_t)b * Te * Den;
    float p[4] = {0, 0, 0, 0};
#pragma unroll 8
    for (int t = 0; t < 128; ++t) {
      int te = teq * 128 + t;
      ushort4 h = *(const ushort4*)(eb + (size_t)te * Den + c0);
      float al = als[te];
      p[0] = fmaf(al, bf2f(h.x), p[0]); p[1] = fmaf(al, bf2f(h.y), p[1]);
      p[2] = fmaf(al, bf2f(h.z), p[2]); p[3] = fmaf(al, bf2f(h.w), p[3]);
    }
    *(float4*)(scr + teq * 256 + c0) = make_float4(p[0], p[1], p[2], p[3]);
  }
  __syncthreads();

  out[(size_t)gtd * 768 + 512 + tid] =
      scr[tid] + scr[256 + tid] + scr[512 + tid] + scr[768 + tid];
}
} // namespace

extern "C" void kernel_launch(void* const* d_in, const int* in_sizes, int n_in,
                              void* d_out, int out_size, void* d_ws, size_t ws_size,
                              hipStream_t stream) {
  const float* en_seq = (const float*)d_in[0];
  const float* de_seq = (const float*)d_in[1];
  const int*   mask   = (const int*)d_in[2];
  const float* w_en   = (const float*)d_in[3];
  const float* w_de   = (const float*)d_in[4];
  const float* nu     = (const float*)d_in[5];
  float* out = (float*)d_out;

  unsigned short* en_pT = (unsigned short*)d_ws;                 // B*U*Te bf16
  unsigned short* en_bf = en_pT + (size_t)B * U * Te;            // B*Te*Den bf16
  float* de_pA = (float*)(en_bf + (size_t)B * Te * Den);         // B*Td*U f32
  float* de_pB = de_pA + (size_t)B * Td * U;                     // B*Td*U f32

  hipLaunchKernelGGL(proj_kernel, dim3(384), dim3(256), 0, stream,
                     en_seq, de_seq, mask, w_en, w_de, en_pT, en_bf,
                     de_pA, de_pB, out);
  hipLaunchKernelGGL(attn_kernel, dim3(512), dim3(256), 0, stream,
                     en_pT, en_bf, de_pA, de_pB, nu, mask, out);
}

// Round 8
// 41.009 us; speedup vs baseline: 1.0401x; 1.0401x over previous
//
#include <hip/hip_runtime.h>

namespace {
constexpr int B = 4, Te = 512, Td = 128, Den = 256, Dde = 512, U = 128;
constexpr float REMOVE = 1000000.0f;
constexpr float L2E2 = 2.885390081777927f;  // 2*log2(e)

__device__ __forceinline__ unsigned short f2bf(float f) {
  unsigned u = __float_as_uint(f);
  u += 0x7FFFu + ((u >> 16) & 1u);      // RNE
  return (unsigned short)(u >> 16);
}
__device__ __forceinline__ float bf2f(unsigned short h) {
  return __uint_as_float(((unsigned)h) << 16);
}
// acc += tanh(ep+dv)*nv ; tanh = 1 - 2/(exp(2x)+1), inf-safe both tails
__device__ __forceinline__ void tanh_fma(float ep, float dv, float nv, float& acc) {
  float e = __builtin_amdgcn_exp2f((ep + dv) * L2E2);
  float r = __builtin_amdgcn_rcpf(e + 1.0f);
  acc = fmaf(fmaf(-2.0f, r, 1.0f), nv, acc);
}
__device__ __forceinline__ void fma4(const float4& w, float x, float* a) {
  a[0] = fmaf(x, w.x, a[0]); a[1] = fmaf(x, w.y, a[1]);
  a[2] = fmaf(x, w.z, a[2]); a[3] = fmaf(x, w.w, a[3]);
}

// ---------------- K1: projections (256 blocks x 256 thr) ----------------
// blocks 0..127:   16 en rows -> en_pT bf16 tiled [b][teT:8][te_in:64][u:128]
//                  + masked bf16 en copy
// blocks 128..255: q=blk-128: rt=q>>1 (8 de rows), kh=q&1 (K-half)
//                  -> de_pA/de_pB f32 + de pass-through to out
__global__ __launch_bounds__(256) void proj_kernel(
    const float* __restrict__ en_seq, const float* __restrict__ de_seq,
    const int* __restrict__ mask, const float* __restrict__ w_en,
    const float* __restrict__ w_de, unsigned short* __restrict__ en_pT,
    unsigned short* __restrict__ en_bf, float* __restrict__ de_pA,
    float* __restrict__ de_pB, float* __restrict__ out) {
  __shared__ float xs[4096];            // 16 KiB
  const int blk = blockIdx.x, tid = threadIdx.x;

  if (blk < 128) {
    const int r0 = blk * 16;            // global encoder rows (b*Te+te)
    for (int i = tid; i < 1024; i += 256) {   // stage masked + bf16 copy
      int row = i >> 6, c4 = i & 63;
      float m = (float)mask[r0 + row];
      float4 v = *(const float4*)(en_seq + (size_t)(r0 + row) * Den + c4 * 4);
      v.x *= m; v.y *= m; v.z *= m; v.w *= m;
      *(float4*)(xs + row * 256 + c4 * 4) = v;
      ushort4 h; h.x = f2bf(v.x); h.y = f2bf(v.y); h.z = f2bf(v.z); h.w = f2bf(v.w);
      *(ushort4*)(en_bf + (size_t)(r0 + row) * Den + c4 * 4) = h;
    }
    __syncthreads();
    const int rg = tid >> 4, ug = tid & 15, u0 = ug * 8;   // 16 rows x 8 u
    float acc[8] = {0, 0, 0, 0, 0, 0, 0, 0};
#pragma unroll 2
    for (int k = 0; k < 256; k += 4) {
      const float* wp = w_en + (size_t)k * U + u0;
      float4 wa0 = *(const float4*)(wp),         wb0 = *(const float4*)(wp + 4);
      float4 wa1 = *(const float4*)(wp + U),     wb1 = *(const float4*)(wp + U + 4);
      float4 wa2 = *(const float4*)(wp + 2 * U), wb2 = *(const float4*)(wp + 2 * U + 4);
      float4 wa3 = *(const float4*)(wp + 3 * U), wb3 = *(const float4*)(wp + 3 * U + 4);
      float4 xv = *(const float4*)(xs + rg * 256 + k);
      fma4(wa0, xv.x, acc); fma4(wb0, xv.x, acc + 4);
      fma4(wa1, xv.y, acc); fma4(wb1, xv.y, acc + 4);
      fma4(wa2, xv.z, acc); fma4(wb2, xv.z, acc + 4);
      fma4(wa3, xv.w, acc); fma4(wb3, xv.w, acc + 4);
    }
    __syncthreads();                    // staging reads done; reuse xs [16][128]
    *(float4*)(xs + rg * 128 + u0)     = make_float4(acc[0], acc[1], acc[2], acc[3]);
    *(float4*)(xs + rg * 128 + u0 + 4) = make_float4(acc[4], acc[5], acc[6], acc[7]);
    __syncthreads();
    {                                   // tiled bf16 write [te_in][u], coalesced
      int r = tid >> 4, uo = (tid & 15) * 8;
      const float* p = xs + r * 128 + uo;
      ushort4 h0, h1;
      h0.x = f2bf(p[0]); h0.y = f2bf(p[1]); h0.z = f2bf(p[2]); h0.w = f2bf(p[3]);
      h1.x = f2bf(p[4]); h1.y = f2bf(p[5]); h1.z = f2bf(p[6]); h1.w = f2bf(p[7]);
      int b = r0 >> 9, teT = (r0 >> 6) & 7, tein0 = r0 & 63;
      unsigned short* dst =
          en_pT + ((size_t)(b * 8 + teT) * 64 + tein0 + r) * U + uo;
      *(ushort4*)dst = h0;
      *(ushort4*)(dst + 4) = h1;
    }
  } else {
    const int q = blk - 128, rt = q >> 1, kh = q & 1;
    const int r0 = rt * 8, k0 = kh * 256;
    for (int i = tid; i < 512; i += 256) {  // stage K-half + pass-through
      int row = i >> 6, c4 = i & 63;
      float4 v = *(const float4*)(de_seq + (size_t)(r0 + row) * Dde + k0 + c4 * 4);
      *(float4*)(xs + row * 256 + c4 * 4) = v;
      *(float4*)(out + (size_t)(r0 + row) * 768 + k0 + c4 * 4) = v;
    }
    __syncthreads();
    const int rg = tid >> 5, ug = tid & 31, u0 = ug * 4;
    float acc[4] = {0, 0, 0, 0};
#pragma unroll 4
    for (int k = 0; k < 256; k += 4) {
      const float* wp = w_de + (size_t)(k0 + k) * U + u0;
      float4 w0 = *(const float4*)(wp);
      float4 w1 = *(const float4*)(wp + U);
      float4 w2 = *(const float4*)(wp + 2 * U);
      float4 w3 = *(const float4*)(wp + 3 * U);
      float4 xv = *(const float4*)(xs + rg * 256 + k);
      fma4(w0, xv.x, acc); fma4(w1, xv.y, acc);
      fma4(w2, xv.z, acc); fma4(w3, xv.w, acc);
    }
    float* dst = kh ? de_pB : de_pA;
    *(float4*)(dst + (size_t)(r0 + rg) * U + u0) =
        make_float4(acc[0], acc[1], acc[2], acc[3]);
  }
}

// ---------------- K2: scores (512 blocks x 256 thr) ----------------
// grid = (b:4) x (tdT:16 of 8 td) x (teT:8 of 64 te)
// en_p tile staged bf16 -> f32 LDS [te][u-quad ^ (te&31)] (conflict-free)
__global__ __launch_bounds__(256) void score_kernel(
    const unsigned short* __restrict__ en_pT, const float* __restrict__ de_pA,
    const float* __restrict__ de_pB, const float* __restrict__ nu,
    const int* __restrict__ mask, float* __restrict__ mu) {
  __shared__ float tile[64 * 128];      // 32 KiB, swizzled
  __shared__ float dep[8 * 128];
  __shared__ float nus[128];
  const int blk = blockIdx.x, tid = threadIdx.x;
  const int teT = blk & 7, tdT = (blk >> 3) & 15, b = blk >> 7;
  const int te0 = teT * 64, td0 = tdT * 8;

  const unsigned short* src = en_pT + (size_t)(b * 8 + teT) * 64 * U;
#pragma unroll
  for (int j = 0; j < 4; ++j) {         // 1024 x 8-elem units = 64 te x 128 u
    int unit = j * 256 + tid;
    int te = unit >> 4, u0 = (unit & 15) * 8;
    ushort4 ha = *(const ushort4*)(src + (size_t)te * U + u0);
    ushort4 hb = *(const ushort4*)(src + (size_t)te * U + u0 + 4);
    int sw = te & 31;
    float4 f0 = make_float4(bf2f(ha.x), bf2f(ha.y), bf2f(ha.z), bf2f(ha.w));
    float4 f1 = make_float4(bf2f(hb.x), bf2f(hb.y), bf2f(hb.z), bf2f(hb.w));
    *(float4*)(tile + te * 128 + (((u0 >> 2) + 0) ^ sw) * 4) = f0;
    *(float4*)(tile + te * 128 + (((u0 >> 2) + 1) ^ sw) * 4) = f1;
  }
  {
    int row = tid >> 5, qq = tid & 31;
    float4 a = *(const float4*)(de_pA + (size_t)(b * Td + td0 + row) * U + qq * 4);
    float4 c = *(const float4*)(de_pB + (size_t)(b * Td + td0 + row) * U + qq * 4);
    *(float4*)(dep + row * 128 + qq * 4) =
        make_float4(a.x + c.x, a.y + c.y, a.z + c.z, a.w + c.w);
    if (tid < 32) *(float4*)(nus + tid * 4) = *(const float4*)(nu + tid * 4);
  }
  __syncthreads();

  const int te = tid & 63, tdq = tid >> 6, sw = te & 31;
  const float4* trow = (const float4*)(tile + te * 128);
  const float* d0 = dep + (tdq * 2 + 0) * 128;
  const float* d1 = dep + (tdq * 2 + 1) * 128;
  float s0 = 0.f, s1 = 0.f;
#pragma unroll 4
  for (int q = 0; q < 32; ++q) {
    float4 ev = trow[q ^ sw];
    float4 av = *(const float4*)(d0 + q * 4);
    float4 bv = *(const float4*)(d1 + q * 4);
    float4 nv = *(const float4*)(nus + q * 4);
    tanh_fma(ev.x, av.x, nv.x, s0); tanh_fma(ev.x, bv.x, nv.x, s1);
    tanh_fma(ev.y, av.y, nv.y, s0); tanh_fma(ev.y, bv.y, nv.y, s1);
    tanh_fma(ev.z, av.z, nv.z, s0); tanh_fma(ev.z, bv.z, nv.z, s1);
    tanh_fma(ev.w, av.w, nv.w, s0); tanh_fma(ev.w, bv.w, nv.w, s1);
  }
  const int gte = te0 + te;
  float bias = ((float)mask[b * Te + gte] - 1.0f) * REMOVE;
  mu[(size_t)(b * Td + td0 + tdq * 2 + 0) * Te + gte] = s0 + bias;
  mu[(size_t)(b * Td + td0 + tdq * 2 + 1) * Te + gte] = s1 + bias;
}

// ---------------- K3: softmax + weighted sum (256 blocks x 512 thr) ----
// grid = (b:4) x (tdT:32 of 4 td) x (chHalf:2 of 128)
__global__ __launch_bounds__(512) void out_kernel(
    const unsigned short* __restrict__ en_bf, const int* __restrict__ mask,
    const float* __restrict__ mu, float* __restrict__ out) {
  __shared__ float al[Te * 4];          // 8 KiB, [te][td]
  __shared__ float part[8 * 4 * 128];   // 16 KiB
  const int blk = blockIdx.x, tid = threadIdx.x;
  const int chH = blk & 1, tdT = (blk >> 1) & 31, b = blk >> 6;
  const int td0 = tdT * 4;
  const int wid = tid >> 6, lane = tid & 63;

  if (wid < 4) {                        // softmax of row td0+wid over Te=512
    const float* murow = mu + (size_t)(b * Td + td0 + wid) * Te;
    const int* mrow = mask + b * Te;
    float v[8]; float mx = -3.0e38f;
#pragma unroll
    for (int i = 0; i < 8; ++i) { v[i] = murow[lane + i * 64]; mx = fmaxf(mx, v[i]); }
#pragma unroll
    for (int o = 32; o >= 1; o >>= 1) mx = fmaxf(mx, __shfl_xor(mx, o));
    float ss = 0.f;
#pragma unroll
    for (int i = 0; i < 8; ++i) { v[i] = __expf(v[i] - mx); ss += v[i]; }
#pragma unroll
    for (int o = 32; o >= 1; o >>= 1) ss += __shfl_xor(ss, o);
    float inv = 1.0f / ss;
#pragma unroll
    for (int i = 0; i < 8; ++i) {
      int te = lane + i * 64;
      al[te * 4 + wid] = v[i] * inv * (float)mrow[te];   // alpha * mask
    }
  }
  __syncthreads();

  {                                     // weighted sum: wave -> 64 te, lane -> 2 ch
    const int c0 = chH * 128 + lane * 2;
    const unsigned short* eb = en_bf + (size_t)b * Te * Den + c0;
    float a00 = 0, a01 = 0, a10 = 0, a11 = 0, a20 = 0, a21 = 0, a30 = 0, a31 = 0;
#pragma unroll 4
    for (int t = 0; t < 64; ++t) {
      int te = wid * 64 + t;
      ushort2 h = *(const ushort2*)(eb + (size_t)te * Den);
      float4 av = *(const float4*)(al + te * 4);
      float e0 = bf2f(h.x), e1 = bf2f(h.y);
      a00 = fmaf(av.x, e0, a00); a01 = fmaf(av.x, e1, a01);
      a10 = fmaf(av.y, e0, a10); a11 = fmaf(av.y, e1, a11);
      a20 = fmaf(av.z, e0, a20); a21 = fmaf(av.z, e1, a21);
      a30 = fmaf(av.w, e0, a30); a31 = fmaf(av.w, e1, a31);
    }
    *(float2*)(part + (wid * 4 + 0) * 128 + lane * 2) = make_float2(a00, a01);
    *(float2*)(part + (wid * 4 + 1) * 128 + lane * 2) = make_float2(a10, a11);
    *(float2*)(part + (wid * 4 + 2) * 128 + lane * 2) = make_float2(a20, a21);
    *(float2*)(part + (wid * 4 + 3) * 128 + lane * 2) = make_float2(a30, a31);
  }
  __syncthreads();

  {
    int td = tid >> 7, cc = tid & 127;
    float r = 0.f;
#pragma unroll
    for (int w = 0; w < 8; ++w) r += part[(w * 4 + td) * 128 + cc];
    out[(size_t)(b * Td + td0 + td) * 768 + 512 + chH * 128 + cc] = r;
  }
}
} // namespace

extern "C" void kernel_launch(void* const* d_in, const int* in_sizes, int n_in,
                              void* d_out, int out_size, void* d_ws, size_t ws_size,
                              hipStream_t stream) {
  const float* en_seq = (const float*)d_in[0];
  const float* de_seq = (const float*)d_in[1];
  const int*   mask   = (const int*)d_in[2];
  const float* w_en   = (const float*)d_in[3];
  const float* w_de   = (const float*)d_in[4];
  const float* nu     = (const float*)d_in[5];
  float* out = (float*)d_out;

  unsigned short* en_pT = (unsigned short*)d_ws;                 // B*Te*U bf16 (tiled)
  unsigned short* en_bf = en_pT + (size_t)B * Te * U;            // B*Te*Den bf16
  float* de_pA = (float*)(en_bf + (size_t)B * Te * Den);         // B*Td*U f32
  float* de_pB = de_pA + (size_t)B * Td * U;                     // B*Td*U f32
  float* mu    = de_pB + (size_t)B * Td * U;                     // B*Td*Te f32

  hipLaunchKernelGGL(proj_kernel, dim3(256), dim3(256), 0, stream,
                     en_seq, de_seq, mask, w_en, w_de, en_pT, en_bf,
                     de_pA, de_pB, out);
  hipLaunchKernelGGL(score_kernel, dim3(512), dim3(256), 0, stream,
                     en_pT, de_pA, de_pB, nu, mask, mu);
  hipLaunchKernelGGL(out_kernel, dim3(256), dim3(512), 0, stream,
                     en_bf, mask, mu, out);
}